// Round 1
// baseline (403.803 us; speedup 1.0000x reference)
//
#include <hip/hip_runtime.h>
#include <hip/hip_bf16.h>

typedef unsigned short u16;
typedef __attribute__((ext_vector_type(4))) float f32x4;
typedef __attribute__((ext_vector_type(8))) short s16x8;  // 8 x bf16 (4 VGPRs)
typedef __attribute__((ext_vector_type(4))) short s16x4;

#define DEVFN static __device__ __forceinline__

DEVFN u16 f2bf(float f) {  // fp32 -> bf16, round-nearest-even
  unsigned u = __float_as_uint(f);
  return (u16)((u + 0x7fffu + ((u >> 16) & 1u)) >> 16);
}
DEVFN float bf2f(u16 h) { return __uint_as_float(((unsigned)h) << 16); }

DEVFN void gl_lds16(const void* g, void* l) {  // async global->LDS, 16B/lane
  __builtin_amdgcn_global_load_lds(
      (const __attribute__((address_space(1))) unsigned int*)g,
      (__attribute__((address_space(3))) unsigned int*)l, 16, 0, 0);
}

DEVFN f32x4 mfma16(s16x8 a, s16x8 b, f32x4 c) {
  return __builtin_amdgcn_mfma_f32_16x16x32_bf16(a, b, c, 0, 0, 0);
}

// ---------------------------------------------------------------- cvt x -> bf16
__global__ void k_cvt_x(const float4* __restrict__ x, u16* __restrict__ xb, int n4) {
  int i = blockIdx.x * 256 + threadIdx.x;
  if (i >= n4) return;
  float4 v = x[i];
  s16x4 o;
  o[0] = (short)f2bf(v.x); o[1] = (short)f2bf(v.y);
  o[2] = (short)f2bf(v.z); o[3] = (short)f2bf(v.w);
  *(s16x4*)(xb + (size_t)i * 4) = o;
}

// ------------------------------------------- transpose+convert weights (f32 KxN -> bf16 NxK)
__global__ void k_transpose_w(const float* __restrict__ src, u16* __restrict__ dst,
                              int K, int N, float scale) {
  __shared__ float tile[64][65];
  int k0 = blockIdx.x * 64, n0 = blockIdx.y * 64;
  int t = threadIdx.x, c = t & 63, r4 = t >> 6;
#pragma unroll
  for (int i = 0; i < 16; ++i) {
    int r = i * 4 + r4;
    tile[r][c] = src[(size_t)(k0 + r) * N + n0 + c] * scale;
  }
  __syncthreads();
#pragma unroll
  for (int i = 0; i < 16; ++i) {
    int r = i * 4 + r4;
    dst[(size_t)(n0 + r) * K + k0 + c] = f2bf(tile[c][r]);
  }
}

// ------------------------------------------- transpose V region of QKV -> Vt [32][512][1024]
__global__ void k_transpose_v(const u16* __restrict__ qkv, u16* __restrict__ vt) {
  __shared__ u16 tile[64][65];
  int bh = blockIdx.z, b = bh >> 3, h = bh & 7;
  int kk0 = blockIdx.x * 64, d0 = blockIdx.y * 64;
  int t = threadIdx.x, c = t & 63, r4 = t >> 6;
#pragma unroll
  for (int i = 0; i < 16; ++i) {
    int r = i * 4 + r4;  // key-local
    tile[r][c] = qkv[(size_t)(b * 1024 + kk0 + r) * 12288 + 8192 + h * 512 + d0 + c];
  }
  __syncthreads();
#pragma unroll
  for (int i = 0; i < 16; ++i) {
    int r = i * 4 + r4;  // d-local
    vt[(size_t)(bh * 512 + d0 + r) * 1024 + kk0 + c] = tile[c][r];
  }
}

// ---------------------------------------------------------------- m97-style GEMM
// C[M][ldc] = A[M][K] @ Bt[N][K]^T   (A, Bt bf16 row-major; B^T layout)
// EPI 0: C bf16;  EPI 1: C f32 + bias
template <int BM, int BN, int EPI>
__global__ void __launch_bounds__(256, 2) k_gemm(
    const u16* __restrict__ A, const u16* __restrict__ Bt,
    void* __restrict__ Cp, const float* __restrict__ bias,
    int M, int N, int K, int ldc) {
  constexpr int MR = BM / 32, NR = BN / 32;      // frags per wave
  constexpr int CHA = BM / 16, CHB = BN / 16;    // 1KB staging chunks
  __shared__ alignas(16) u16 Alds[BM * 32];
  __shared__ alignas(16) u16 Blds[BN * 32];
  const int tid = threadIdx.x, lane = tid & 63, wv = tid >> 6;
  const int wr = wv >> 1, wc = wv & 1;
  const int row0 = blockIdx.y * BM, col0 = blockIdx.x * BN;
  const char* Ab = (const char*)A;
  const char* Bb = (const char*)Bt;
  const f32x4 zero4 = {0.f, 0.f, 0.f, 0.f};
  f32x4 acc[MR][NR];
#pragma unroll
  for (int m = 0; m < MR; ++m)
#pragma unroll
    for (int n = 0; n < NR; ++n) acc[m][n] = zero4;

  for (int k0 = 0; k0 < K; k0 += 32) {
#pragma unroll
    for (int j = 0; j < CHA / 4; ++j) {
      int ch = j * 4 + wv;
      int r = ch * 16 + (lane >> 2);
      int cb = (lane & 3) * 16;
      gl_lds16(Ab + ((size_t)(row0 + r) * K + k0) * 2 + cb, (char*)Alds + ch * 1024);
    }
#pragma unroll
    for (int j = 0; j < CHB / 4; ++j) {
      int ch = j * 4 + wv;
      int r = ch * 16 + (lane >> 2);
      int cb = (lane & 3) * 16;
      gl_lds16(Bb + ((size_t)(col0 + r) * K + k0) * 2 + cb, (char*)Blds + ch * 1024);
    }
    __syncthreads();
    s16x8 af[MR], bfr[NR];
#pragma unroll
    for (int m = 0; m < MR; ++m)
      af[m] = *(const s16x8*)((const char*)Alds +
               (wr * (BM / 2) + m * 16 + (lane & 15)) * 64 + (lane >> 4) * 16);
#pragma unroll
    for (int n = 0; n < NR; ++n)
      bfr[n] = *(const s16x8*)((const char*)Blds +
                (wc * (BN / 2) + n * 16 + (lane & 15)) * 64 + (lane >> 4) * 16);
#pragma unroll
    for (int m = 0; m < MR; ++m)
#pragma unroll
      for (int n = 0; n < NR; ++n) acc[m][n] = mfma16(af[m], bfr[n], acc[m][n]);
    __syncthreads();
  }
#pragma unroll
  for (int m = 0; m < MR; ++m)
#pragma unroll
    for (int n = 0; n < NR; ++n)
#pragma unroll
      for (int i = 0; i < 4; ++i) {
        int r = row0 + wr * (BM / 2) + m * 16 + (lane >> 4) * 4 + i;
        int c = col0 + wc * (BN / 2) + n * 16 + (lane & 15);
        if (EPI == 0)
          ((u16*)Cp)[(size_t)r * ldc + c] = f2bf(acc[m][n][i]);
        else
          ((float*)Cp)[(size_t)r * ldc + c] = acc[m][n][i] + bias[c];
      }
}

// ---------------------------------------------------------------- flash attention
// grid 256: bh = bid>>3 (32), qp = bid&7; each block does q-tiles {qp, 15-qp} (64 rows each)
// 8 waves: qs = wv>>2 (32 q-rows), kg = wv&3 (16 keys in QK / 128-d slice in PV)
__global__ void __launch_bounds__(512, 2) k_attn(
    const u16* __restrict__ qkv, const u16* __restrict__ vt, u16* __restrict__ O) {
  __shared__ alignas(128) unsigned char kvb[65536];  // K tile [64][1024B] / Vt tile [512][128B]
  __shared__ alignas(16) u16 sp[4096];               // S/P [64][64] bf16, XOR-swizzled
  __shared__ alignas(16) float mrun[64];
  __shared__ alignas(16) float lrun[64];
  __shared__ alignas(16) float alf[64];

  const int tid = threadIdx.x, lane = tid & 63, wv = tid >> 6;
  const int qs = wv >> 2, kg = wv & 3;
  const int bh = blockIdx.x >> 3, qp = blockIdx.x & 7;
  const int b = bh >> 3, h = bh & 7;
  const char* const qkvb = (const char*)qkv;
  const char* const vtb = (const char*)vt;
  const f32x4 zero4 = {0.f, 0.f, 0.f, 0.f};

  for (int half = 0; half < 2; ++half) {
    const int qt = half ? (15 - qp) : qp;
    __syncthreads();  // previous half fully done with LDS
    if (tid < 64) { mrun[tid] = -3e38f; lrun[tid] = 0.f; }

    // Q fragments straight from global (fresh in L2; 16 rows x 64B per instr)
    s16x8 qf[2][16];
    {
      const char* qbase = qkvb + ((size_t)(b * 1024 + qt * 64) * 12288 + h * 512) * 2;
#pragma unroll
      for (int mr = 0; mr < 2; ++mr) {
        const int r = qs * 32 + mr * 16 + (lane & 15);
        const char* rp = qbase + (size_t)r * 24576 + (lane >> 4) * 16;
#pragma unroll
        for (int kk = 0; kk < 16; ++kk) qf[mr][kk] = *(const s16x8*)(rp + kk * 64);
      }
    }
    f32x4 oacc[2][8];
#pragma unroll
    for (int mr = 0; mr < 2; ++mr)
#pragma unroll
      for (int dg = 0; dg < 8; ++dg) oacc[mr][dg] = zero4;

    const int ntiles = qt + 1;
    for (int t = 0; t < ntiles; ++t) {
      const int kv0 = t * 64;
      __syncthreads();  // prev PV reads / init visible before restaging
      {  // stage K tile (swizzled source -> linear LDS; read applies same XOR)
        const char* kbase = qkvb + ((size_t)(b * 1024 + kv0) * 12288 + 4096 + h * 512) * 2;
#pragma unroll
        for (int j = 0; j < 8; ++j) {
          const int c = wv * 8 + j;  // key row
          const unsigned w = (unsigned)(lane * 16) ^ ((c & 7) << 4);
          gl_lds16(kbase + (size_t)c * 24576 + w, kvb + c * 1024);
        }
      }
      __syncthreads();
      // S = Q @ K^T  (full 512-d reduction in-wave; wave owns 16 keys)
      f32x4 sacc0 = zero4, sacc1 = zero4;
      {
        const int kr = kg * 16 + (lane & 15);
        const unsigned roff = (unsigned)kr * 1024u;
#pragma unroll
        for (int kk = 0; kk < 16; ++kk) {
          const s16x8 kf = *(const s16x8*)(kvb + roff +
              ((unsigned)(kk * 64 + (lane >> 4) * 16) ^ ((kr & 7) << 4)));
          sacc0 = mfma16(qf[0][kk], kf, sacc0);
          sacc1 = mfma16(qf[1][kk], kf, sacc1);
        }
      }
      {  // causal mask + store S (bf16, swizzled)
        const int col = kg * 16 + (lane & 15);
        const int kgl = kv0 + col;
#pragma unroll
        for (int mr = 0; mr < 2; ++mr)
#pragma unroll
          for (int i = 0; i < 4; ++i) {
            const int ql = qs * 32 + mr * 16 + (lane >> 4) * 4 + i;
            float s = (mr == 0) ? sacc0[i] : sacc1[i];
            if (kgl > qt * 64 + ql) s = -3e38f;
            *(u16*)((char*)sp + ql * 128 + ((unsigned)(col * 2) ^ ((ql & 7) << 4))) = f2bf(s);
          }
      }
      __syncthreads();
      {  // stage Vt tile (async; overlaps softmax below)
        const char* vbase = vtb + ((size_t)bh * 512 * 1024 + kv0) * 2;
#pragma unroll
        for (int j = 0; j < 8; ++j) {
          const int c = wv * 8 + j;
          const int d = c * 8 + (lane >> 3);
          const unsigned w = (unsigned)((lane & 7) * 16) ^ ((d & 7) << 4);
          gl_lds16(vbase + (size_t)d * 2048 + w, kvb + c * 1024);
        }
      }
      {  // online softmax: 8 lanes per row
        const int r = tid >> 3, sub = tid & 7;
        char* rowp = (char*)sp + r * 128;
        const unsigned off = (unsigned)(sub * 16) ^ ((r & 7) << 4);
        s16x8 sv = *(const s16x8*)(rowp + off);
        float sf[8];
#pragma unroll
        for (int j = 0; j < 8; ++j) sf[j] = bf2f((u16)sv[j]);
        float mt = sf[0];
#pragma unroll
        for (int j = 1; j < 8; ++j) mt = fmaxf(mt, sf[j]);
        mt = fmaxf(mt, __shfl_xor(mt, 1));
        mt = fmaxf(mt, __shfl_xor(mt, 2));
        mt = fmaxf(mt, __shfl_xor(mt, 4));
        const float mo = mrun[r];
        const float mn = fmaxf(mo, mt);
        float sum = 0.f;
        s16x8 pb;
#pragma unroll
        for (int j = 0; j < 8; ++j) {
          const float p = __expf(sf[j] - mn);
          sum += p;
          pb[j] = (short)f2bf(p);
        }
        *(s16x8*)(rowp + off) = pb;  // P in place of S
        sum += __shfl_xor(sum, 1);
        sum += __shfl_xor(sum, 2);
        sum += __shfl_xor(sum, 4);
        if (sub == 0) {
          const float a = __expf(mo - mn);
          alf[r] = a;
          lrun[r] = lrun[r] * a + sum;
          mrun[r] = mn;
        }
      }
      __syncthreads();
      // rescale O, then O += P @ V (wave owns 128-d slice d0 = kg*128)
#pragma unroll
      for (int mr = 0; mr < 2; ++mr) {
        const f32x4 a4 = *(const f32x4*)&alf[qs * 32 + mr * 16 + (lane >> 4) * 4];
#pragma unroll
        for (int dg = 0; dg < 8; ++dg) oacc[mr][dg] *= a4;
      }
      s16x8 pf[2][2];
#pragma unroll
      for (int mr = 0; mr < 2; ++mr) {
        const int q = qs * 32 + mr * 16 + (lane & 15);
#pragma unroll
        for (int k2 = 0; k2 < 2; ++k2)
          pf[mr][k2] = *(const s16x8*)((const char*)sp + q * 128 +
              ((unsigned)(k2 * 64 + (lane >> 4) * 16) ^ ((q & 7) << 4)));
      }
#pragma unroll
      for (int dg = 0; dg < 8; ++dg) {
        const int d = kg * 128 + dg * 16 + (lane & 15);
        const unsigned doff = (unsigned)d * 128u;
#pragma unroll
        for (int k2 = 0; k2 < 2; ++k2) {
          const s16x8 vf = *(const s16x8*)(kvb + doff +
              ((unsigned)(k2 * 64 + (lane >> 4) * 16) ^ ((d & 7) << 4)));
          oacc[0][dg] = mfma16(pf[0][k2], vf, oacc[0][dg]);
          oacc[1][dg] = mfma16(pf[1][k2], vf, oacc[1][dg]);
        }
      }
    }
    // normalize + write O tile (bf16)
#pragma unroll
    for (int mr = 0; mr < 2; ++mr) {
      const f32x4 l4 = *(const f32x4*)&lrun[qs * 32 + mr * 16 + (lane >> 4) * 4];
#pragma unroll
      for (int dg = 0; dg < 8; ++dg) {
        const int colo = h * 512 + kg * 128 + dg * 16 + (lane & 15);
#pragma unroll
        for (int i = 0; i < 4; ++i) {
          const int row = b * 1024 + qt * 64 + qs * 32 + mr * 16 + (lane >> 4) * 4 + i;
          O[(size_t)row * 4096 + colo] = f2bf(oacc[mr][dg][i] / l4[i]);
        }
      }
    }
  }
}

// ---------------------------------------------------------------- launch
extern "C" void kernel_launch(void* const* d_in, const int* in_sizes, int n_in,
                              void* d_out, int out_size, void* d_ws, size_t ws_size,
                              hipStream_t stream) {
  (void)in_sizes; (void)n_in; (void)out_size; (void)ws_size;
  const float* x  = (const float*)d_in[0];
  const float* Wq = (const float*)d_in[1];
  const float* Wk = (const float*)d_in[2];
  const float* Wv = (const float*)d_in[3];
  const float* Wo = (const float*)d_in[4];
  const float* bo = (const float*)d_in[5];
  float* out = (float*)d_out;

  // workspace layout (u16 elements); total 188,743,680 bytes
  u16* ws   = (u16*)d_ws;
  u16* xb   = ws;                    // 4096*512
  u16* WT   = xb + 2097152;          // 12288*512  (WqT | WkT | WvT)
  u16* WoT  = WT + 6291456;          // 512*4096
  u16* QKV  = WoT + 2097152;         // 4096*12288
  u16* VT   = QKV + 50331648;        // 32*512*1024
  u16* Obuf = VT + 16777216;         // 4096*4096

  const float qscale = 0.044194173824159216f;  // 1/sqrt(512)

  k_cvt_x<<<2048, 256, 0, stream>>>((const float4*)x, xb, 524288);

  dim3 gw(8, 64);  // K/64=8, N/64=64
  k_transpose_w<<<gw, 256, 0, stream>>>(Wq, WT,            512, 4096, qscale);
  k_transpose_w<<<gw, 256, 0, stream>>>(Wk, WT + 2097152,  512, 4096, 1.f);
  k_transpose_w<<<gw, 256, 0, stream>>>(Wv, WT + 4194304,  512, 4096, 1.f);
  dim3 gwo(64, 8);
  k_transpose_w<<<gwo, 256, 0, stream>>>(Wo, WoT, 4096, 512, 1.f);

  dim3 g1(96, 32);  // N/128, M/128
  k_gemm<128, 128, 0><<<g1, 256, 0, stream>>>(xb, WT, (void*)QKV, nullptr,
                                              4096, 12288, 512, 12288);

  dim3 gv(16, 8, 32);  // k-tiles, d-tiles, bh
  k_transpose_v<<<gv, 256, 0, stream>>>(QKV, VT);

  k_attn<<<256, 512, 0, stream>>>(QKV, VT, Obuf);

  dim3 g2(8, 32);  // N/64, M/128
  k_gemm<128, 64, 1><<<g2, 256, 0, stream>>>(Obuf, WoT, (void*)out, bo,
                                             4096, 512, 4096, 512);
}